// Round 19
// baseline (49.634 us; speedup 1.0000x reference)
//
#include <hip/hip_runtime.h>

#define B_ 2
#define Q_ 2048
#define K_ 2048
#define H_ 16
#define D_ 64
#define HD_ (H_ * D_)

// Q pre-scale: (1/sqrt(64)) * log2(e)  -> scores in log2 units; softmax uses
// raw v_exp_f32 (2^x) with no per-element multiply.
#define QSCALE 0.18033688011112042f
#define DEFER_THR 10.0f   // log2-units; P bounded by 2^10, fine in bf16/f32

typedef __bf16 bf16_t;
typedef __attribute__((ext_vector_type(8))) __bf16 bf16x8;
typedef __attribute__((ext_vector_type(4))) __bf16 bf16x4;
typedef __attribute__((ext_vector_type(4))) float f32x4;
typedef __attribute__((ext_vector_type(4))) unsigned int u32x4;

// Raw barrier: drains LDS ops only; global register-prefetch stays in flight.
#define SBAR() do {                                         \
    __builtin_amdgcn_sched_barrier(0);                      \
    asm volatile("s_waitcnt lgkmcnt(0)" ::: "memory");      \
    __builtin_amdgcn_s_barrier();                           \
    __builtin_amdgcn_sched_barrier(0);                      \
} while (0)

// Swizzles: XOR bits 4-6 of the byte offset with row&7 — bijective, keeps 16B
// granules, spreads a column access across 8 bank slots (2-way residual = free).
// K tile rows are 128 B (64 bf16); V tile rows are 256 B (128 bf16 keys).
__device__ __forceinline__ int swzK(int row, int colByte) {
    return (row * 128 + colByte) ^ ((row & 7) << 4);
}
__device__ __forceinline__ int swzV(int row, int colByte) {
    return (row * 256 + colByte) ^ ((row & 7) << 4);
}

// r18 frame (512 thr / 8 waves / F=1 / BQ=128 / P-in-regs / XCD remap v2)
// with KVBLK 64 -> 128: halves the per-key count of {SBAR drains, softmax
// gates, prefetch issues} while per-key MFMA/exp/pack work is unchanged.
// LDS 64 KB -> still 2 blocks/CU; reg[8] in-flight prefetch (~+32 VGPR, safe
// under single-arg launch bounds per r14).
__global__ __launch_bounds__(512) void attn_fwd_kernel(
    const float* __restrict__ qs, const float* __restrict__ ks,
    const float* __restrict__ vs, const int* __restrict__ valid_lens,
    float* __restrict__ out)
{
    // ---- XCD remap v2 (r18-proven): 2 heads/XCD locality, batch flips
    // between co-resident blocks p and p+256. Bijective: 8*2*2*16 = 512.
    const int p    = blockIdx.x;
    const int xcd  = p & 7;
    const int slot = p >> 3;                  // 0..63
    const int qt   = slot & 15;               // q-tile within group
    const int h    = xcd * 2 + ((slot >> 4) & 1);
    const int b    = (slot >> 5) & 1;

    const int tid  = threadIdx.x;
    const int lane = tid & 63;
    const int l16  = lane & 15;
    const int lhi  = lane >> 4;    // 0..3

    const int valid  = valid_lens[b];
    const int ntiles = (valid + 127) >> 7;   // 128-key tiles; fully-masked tiles contribute 0

    __shared__ bf16_t k_lds[2][128 * 64];   // [buf][key][d], swizzled (128 B rows)
    __shared__ bf16_t v_lds[2][64 * 128];   // [buf][d][key] transposed, swizzled (256 B rows)

    // ---- Q fragment (lane = row l16, k-dim d = dh*32+lhi*8+j), scale folded.
    const int    qrow = qt * 128 + (tid >> 6) * 16 + l16;
    const float* qp   = qs + (((size_t)b * Q_ + qrow) * H_ + h) * D_;
    bf16x8 a_q[2];
    #pragma unroll
    for (int dh = 0; dh < 2; ++dh) {
        const f32x4* q4 = (const f32x4*)(qp + dh * 32 + lhi * 8);
        f32x4 lo = q4[0], hi = q4[1];
        #pragma unroll
        for (int j = 0; j < 4; ++j) {
            a_q[dh][j]     = (bf16_t)(lo[j] * QSCALE);
            a_q[dh][4 + j] = (bf16_t)(hi[j] * QSCALE);
        }
    }

    // O accumulator (swapped PV C-layout): lane = q-col l16, d = t*16+lhi*4+r.
    f32x4 o_acc[4];
    #pragma unroll
    for (int t = 0; t < 4; ++t) o_acc[t] = (f32x4){0.f, 0.f, 0.f, 0.f};
    float m_r = -1e30f, l_part = 0.f;

    const float* kb = ks + ((size_t)b * K_ * H_ + h) * D_;
    const float* vg = vs + ((size_t)b * K_ * H_ + h) * D_;

    // staging role split (wave-uniform): waves 0-3 stage K, waves 4-7 stage V.
    // Per 128-key tile each thread moves 8 f32x4 (reg[8] in flight).
    const bool kRole = (tid < 256);
    const int  st    = kRole ? tid : (tid - 256);   // 0..255
    const int  krow  = st >> 1;                     // 0..127 (key)
    const int  kcolf = (st & 1) * 32;               // float col base (32 floats)
    const int  vr    = (st & 31) * 4;               // key base (4 rows)
    const int  vc    = (st >> 5) * 8;               // d base (8 cols)

    f32x4 reg[8];   // in-flight next tile (lives across the barrier)

    auto issue_loads = [&](int kt) {
        if (kRole) {
            const float* ksrc = kb + (size_t)(kt * 128 + krow) * HD_ + kcolf;
            #pragma unroll
            for (int i = 0; i < 8; ++i) reg[i] = ((const f32x4*)ksrc)[i];
        } else {
            #pragma unroll
            for (int i = 0; i < 4; ++i) {
                const float* vsrc = vg + (size_t)(kt * 128 + vr + i) * HD_ + vc;
                reg[2 * i]     = ((const f32x4*)vsrc)[0];
                reg[2 * i + 1] = ((const f32x4*)vsrc)[1];
            }
        }
    };

    auto write_tile = [&](int bi) {
        if (kRole) {
            char* kdst = (char*)&k_lds[bi][0];
            #pragma unroll
            for (int pq = 0; pq < 4; ++pq) {
                bf16x8 w;
                #pragma unroll
                for (int j = 0; j < 4; ++j) {
                    w[j]     = (bf16_t)reg[2 * pq][j];
                    w[4 + j] = (bf16_t)reg[2 * pq + 1][j];
                }
                *(bf16x8*)(kdst + swzK(krow, kcolf * 2 + pq * 16)) = w;
            }
        } else {
            char* vdst = (char*)&v_lds[bi][0];
            #pragma unroll
            for (int j = 0; j < 4; ++j) {
                bf16x4 w;
                #pragma unroll
                for (int r = 0; r < 4; ++r) w[r] = (bf16_t)reg[2 * r][j];
                *(bf16x4*)(vdst + swzV(vc + j, vr * 2)) = w;
            }
            #pragma unroll
            for (int j = 0; j < 4; ++j) {
                bf16x4 w;
                #pragma unroll
                for (int r = 0; r < 4; ++r) w[r] = (bf16_t)reg[2 * r + 1][j];
                *(bf16x4*)(vdst + swzV(vc + 4 + j, vr * 2)) = w;
            }
        }
    };

    // prologue: tile 0 straight to LDS
    issue_loads(0);
    write_tile(0);
    int cur = 0;

    for (int kt = 0; kt < ntiles; ++kt) {
        const bool more = (kt + 1 < ntiles);
        if (more) issue_loads(kt + 1);   // stays in flight across SBAR (no vmcnt drain)
        SBAR();

        char* const kbase = (char*)&k_lds[cur][0];
        char* const vbase = (char*)&v_lds[cur][0];

        // ---- S^T = K Q^T (swapped): lane = q-row l16, keys n*16+lhi*4+r,
        // n = 0..7 covering 128 keys.
        f32x4 s[8];
        #pragma unroll
        for (int n = 0; n < 8; ++n) s[n] = (f32x4){0.f, 0.f, 0.f, 0.f};
        __builtin_amdgcn_s_setprio(1);
        #pragma unroll
        for (int n = 0; n < 8; ++n) {
            #pragma unroll
            for (int dh = 0; dh < 2; ++dh) {
                bf16x8 ak = *(const bf16x8*)(kbase + swzK(n * 16 + l16, dh * 64 + lhi * 16));
                s[n] = __builtin_amdgcn_mfma_f32_16x16x32_bf16(ak, a_q[dh], s[n], 0, 0, 0);
            }
        }
        __builtin_amdgcn_s_setprio(0);

        // ---- mask only on the boundary tile (uniform branch) ----
        if (kt * 128 + 128 > valid) {
            #pragma unroll
            for (int n = 0; n < 8; ++n) {
                const int kbase_i = kt * 128 + n * 16 + lhi * 4;
                #pragma unroll
                for (int r = 0; r < 4; ++r)
                    if (kbase_i + r >= valid) s[n][r] = -1e30f;
            }
        }

        // ---- deferred-max online softmax, all state lane-local; ONE gate
        // per 128 keys (2x fewer votes/rescale checks than KVBLK=64).
        float lm = s[0][0];
        #pragma unroll
        for (int n = 0; n < 8; ++n)
            #pragma unroll
            for (int r = 0; r < 4; ++r) lm = fmaxf(lm, s[n][r]);
        if (__any(lm > m_r + DEFER_THR)) {   // rare, wave-uniform update
            float rm = fmaxf(lm, __shfl_xor(lm, 16, 64));
            rm = fmaxf(rm, __shfl_xor(rm, 32, 64));
            const float mnew  = fmaxf(m_r, rm);
            const float alpha = __builtin_amdgcn_exp2f(m_r - mnew);
            m_r = mnew;
            l_part *= alpha;
            #pragma unroll
            for (int t = 0; t < 4; ++t) o_acc[t] *= alpha;
        }

        // ---- P = 2^(s-m) -> bf16 B-fragments IN REGISTERS (no LDS):
        // cvt_pk packs pairs; permlane32+16 swaps -> pb[kk] = keys
        // kk*32 + lhi*8 + j, kk = 0..3 (verified pattern, r11).
        bf16x8 pb[4];
        {
            float psum = 0.f;
            unsigned pk[8][2];
            #pragma unroll
            for (int n = 0; n < 8; ++n) {
                float e0 = __builtin_amdgcn_exp2f(s[n][0] - m_r);
                float e1 = __builtin_amdgcn_exp2f(s[n][1] - m_r);
                float e2 = __builtin_amdgcn_exp2f(s[n][2] - m_r);
                float e3 = __builtin_amdgcn_exp2f(s[n][3] - m_r);
                psum += (e0 + e1) + (e2 + e3);
                asm("v_cvt_pk_bf16_f32 %0, %1, %2" : "=v"(pk[n][0]) : "v"(e0), "v"(e1));
                asm("v_cvt_pk_bf16_f32 %0, %1, %2" : "=v"(pk[n][1]) : "v"(e2), "v"(e3));
            }
            l_part += psum;
            #pragma unroll
            for (int kk = 0; kk < 4; ++kk) {
                unsigned a0 = pk[2 * kk][0],     a1 = pk[2 * kk][1];
                unsigned b0 = pk[2 * kk + 1][0], b1 = pk[2 * kk + 1][1];
                asm("v_permlane32_swap_b32 %0, %1" : "+v"(a0), "+v"(b0));
                asm("v_permlane16_swap_b32 %0, %1" : "+v"(a0), "+v"(b0));
                asm("v_permlane32_swap_b32 %0, %1" : "+v"(a1), "+v"(b1));
                asm("v_permlane16_swap_b32 %0, %1" : "+v"(a1), "+v"(b1));
                u32x4 words = {a0, a1, b0, b1};   // j01, j23, j45, j67
                pb[kk] = __builtin_bit_cast(bf16x8, words);
            }
        }

        // ---- PV swapped: O^T += V^T P^T -> lane = q-col, d-rows ----
        __builtin_amdgcn_s_setprio(1);
        #pragma unroll
        for (int t = 0; t < 4; ++t) {
            #pragma unroll
            for (int kk = 0; kk < 4; ++kk) {
                bf16x8 vb = *(const bf16x8*)(vbase + swzV(t * 16 + l16, kk * 64 + lhi * 16));
                o_acc[t] = __builtin_amdgcn_mfma_f32_16x16x32_bf16(vb, pb[kk], o_acc[t], 0, 0, 0);
            }
        }
        __builtin_amdgcn_s_setprio(0);

        // regs -> LDS for next tile; vmcnt paid HERE (after full compute phase)
        if (more) write_tile(cur ^ 1);
        cur ^= 1;
    }

    // ---- epilogue: finish l over the lhi group, divide, vector store ----
    float l = l_part;
    l += __shfl_xor(l, 16, 64);
    l += __shfl_xor(l, 32, 64);
    const float inv = 1.f / l;
    float* op = out + (((size_t)b * Q_ + qrow) * H_ + h) * D_;
    #pragma unroll
    for (int t = 0; t < 4; ++t) {
        f32x4 res = o_acc[t];
        #pragma unroll
        for (int r = 0; r < 4; ++r) res[r] *= inv;
        *(f32x4*)(op + t * 16 + lhi * 4) = res;
    }
}

extern "C" void kernel_launch(void* const* d_in, const int* in_sizes, int n_in,
                              void* d_out, int out_size, void* d_ws, size_t ws_size,
                              hipStream_t stream) {
    const float* qs = (const float*)d_in[0];
    const float* ks = (const float*)d_in[1];
    const float* vs = (const float*)d_in[2];
    const int*   vl = (const int*)d_in[3];
    float*       out = (float*)d_out;
    attn_fwd_kernel<<<dim3(512), 512, 0, stream>>>(qs, ks, vs, vl, out);
}

// Round 20
// 35.338 us; speedup vs baseline: 1.4046x; 1.4046x over previous
//
#include <hip/hip_runtime.h>

#define B_ 2
#define Q_ 2048
#define K_ 2048
#define H_ 16
#define D_ 64
#define HD_ (H_ * D_)

// Q pre-scale: (1/sqrt(64)) * log2(e)  -> scores in log2 units; softmax uses
// raw v_exp_f32 (2^x) with no per-element multiply.
#define QSCALE 0.18033688011112042f
#define DEFER_THR 10.0f   // log2-units; P bounded by 2^10, fine in bf16/f32

typedef __bf16 bf16_t;
typedef __attribute__((ext_vector_type(8))) __bf16 bf16x8;
typedef __attribute__((ext_vector_type(4))) __bf16 bf16x4;
typedef __attribute__((ext_vector_type(4))) float f32x4;
typedef __attribute__((ext_vector_type(4))) unsigned int u32x4;

// Raw barrier: drains LDS ops only; global register-prefetch stays in flight.
#define SBAR() do {                                         \
    __builtin_amdgcn_sched_barrier(0);                      \
    asm volatile("s_waitcnt lgkmcnt(0)" ::: "memory");      \
    __builtin_amdgcn_s_barrier();                           \
    __builtin_amdgcn_sched_barrier(0);                      \
} while (0)

// Swizzled byte offset for a [N][64] bf16 tile (row stride 128 B).
// XOR bits 4-6 with row&7: bijective, keeps 16B granules, kills bank conflicts.
__device__ __forceinline__ int swz(int row, int colByte) {
    return (row * 128 + colByte) ^ ((row & 7) << 4);
}

// CONVERGED FORM (r18, 35.3 us): 512 thr / 8 waves / F=1 / BQ=128 / KVBLK=64,
// monolith. Techniques, each A/B-proven on this problem:
//  - XOR-swizzled K + transposed-V LDS tiles, conflict-free (r1: 1.4e7 -> 0)
//  - lgkm-only SBAR + cross-barrier register prefetch (r3-r5 frame)
//  - 8-wave TLP, K/V staging role split (r5: +36%)
//  - exp2-domain scores, deferred-max gate, lane-partial l (r6: +27%)
//  - swapped-operand QK^T/PV -> lane-local softmax state, vector stores (r7)
//  - P->B-fragments in registers via cvt_pk + permlane{32,16}_swap (r15: +6%;
//    numerics verified r11). SINGLE-ARG launch bounds only - two-arg capped
//    arch-VGPRs at 64 and spilled ~50 regs/thread (r9-r14).
//  - XCD remap v2: 2 heads/XCD L2 locality (FETCH 63.5->15.1 MB) with batch
//    flipped between co-resident blocks p/p+256 for short/long backfill (r18).
// Rejected by measurement: BQ=64 (r8), split-K (r9-r13), F=2 (r11-r14),
// two-half softmax pipeline (r16), same-batch XCD pairing (r17), KVBLK=128 (r19).
__global__ __launch_bounds__(512) void attn_fwd_kernel(
    const float* __restrict__ qs, const float* __restrict__ ks,
    const float* __restrict__ vs, const int* __restrict__ valid_lens,
    float* __restrict__ out)
{
    const int p    = blockIdx.x;
    const int xcd  = p & 7;
    const int slot = p >> 3;                  // 0..63
    const int qt   = slot & 15;               // q-tile within group
    const int h    = xcd * 2 + ((slot >> 4) & 1);
    const int b    = (slot >> 5) & 1;

    const int tid  = threadIdx.x;
    const int lane = tid & 63;
    const int l16  = lane & 15;
    const int lhi  = lane >> 4;    // 0..3

    const int valid  = valid_lens[b];
    const int ntiles = (valid + 63) >> 6;   // tiles fully past valid contribute exactly 0

    __shared__ bf16_t k_lds[2][64 * 64];    // [buf][key][d], swizzled
    __shared__ bf16_t v_lds[2][64 * 64];    // [buf][d][key] transposed, swizzled

    // ---- Q fragment (lane = row l16, k-dim d = dh*32+lhi*8+j), scale folded.
    const int    qrow = qt * 128 + (tid >> 6) * 16 + l16;
    const float* qp   = qs + (((size_t)b * Q_ + qrow) * H_ + h) * D_;
    bf16x8 a_q[2];
    #pragma unroll
    for (int dh = 0; dh < 2; ++dh) {
        const f32x4* q4 = (const f32x4*)(qp + dh * 32 + lhi * 8);
        f32x4 lo = q4[0], hi = q4[1];
        #pragma unroll
        for (int j = 0; j < 4; ++j) {
            a_q[dh][j]     = (bf16_t)(lo[j] * QSCALE);
            a_q[dh][4 + j] = (bf16_t)(hi[j] * QSCALE);
        }
    }

    // O accumulator (swapped PV C-layout): lane = q-col l16, d = t*16+lhi*4+r.
    f32x4 o_acc[4];
    #pragma unroll
    for (int t = 0; t < 4; ++t) o_acc[t] = (f32x4){0.f, 0.f, 0.f, 0.f};
    float m_r = -1e30f, l_part = 0.f;

    const float* kb = ks + ((size_t)b * K_ * H_ + h) * D_;
    const float* vg = vs + ((size_t)b * K_ * H_ + h) * D_;

    // staging role split (wave-uniform): waves 0-3 stage K, waves 4-7 stage V
    const bool kRole = (tid < 256);
    const int  st    = kRole ? tid : (tid - 256);   // 0..255
    const int  krow  = st >> 2;                     // 0..63 (key)
    const int  kcolf = (st & 3) * 16;               // float col base
    const int  vr    = (st & 15) * 4;               // key base (4 rows)
    const int  vc    = (st >> 4) * 4;               // d base (4 cols)

    f32x4 reg[4];   // in-flight next tile (lives across the barrier)

    auto issue_loads = [&](int kt) {
        if (kRole) {
            const float* ksrc = kb + (size_t)(kt * 64 + krow) * HD_ + kcolf;
            #pragma unroll
            for (int i = 0; i < 4; ++i) reg[i] = ((const f32x4*)ksrc)[i];
        } else {
            #pragma unroll
            for (int i = 0; i < 4; ++i)
                reg[i] = *(const f32x4*)(vg + (size_t)(kt * 64 + vr + i) * HD_ + vc);
        }
    };

    auto write_tile = [&](int bi) {
        if (kRole) {
            char* kdst = (char*)&k_lds[bi][0];
            bf16x8 lo, hi;
            #pragma unroll
            for (int j = 0; j < 4; ++j) {
                lo[j] = (bf16_t)reg[0][j]; lo[4 + j] = (bf16_t)reg[1][j];
                hi[j] = (bf16_t)reg[2][j]; hi[4 + j] = (bf16_t)reg[3][j];
            }
            *(bf16x8*)(kdst + swz(krow, kcolf * 2))      = lo;
            *(bf16x8*)(kdst + swz(krow, kcolf * 2 + 16)) = hi;
        } else {
            char* vdst = (char*)&v_lds[bi][0];
            #pragma unroll
            for (int j = 0; j < 4; ++j) {
                bf16x4 w;
                w[0] = (bf16_t)reg[0][j]; w[1] = (bf16_t)reg[1][j];
                w[2] = (bf16_t)reg[2][j]; w[3] = (bf16_t)reg[3][j];
                *(bf16x4*)(vdst + swz(vc + j, vr * 2)) = w;
            }
        }
    };

    // prologue: tile 0 straight to LDS
    issue_loads(0);
    write_tile(0);
    int cur = 0;

    for (int kt = 0; kt < ntiles; ++kt) {
        const bool more = (kt + 1 < ntiles);
        if (more) issue_loads(kt + 1);   // stays in flight across SBAR (no vmcnt drain)
        SBAR();

        char* const kbase = (char*)&k_lds[cur][0];
        char* const vbase = (char*)&v_lds[cur][0];

        // ---- S^T = K Q^T (swapped): lane = q-row l16, keys n*16+lhi*4+r.
        f32x4 s[4];
        #pragma unroll
        for (int n = 0; n < 4; ++n) s[n] = (f32x4){0.f, 0.f, 0.f, 0.f};
        __builtin_amdgcn_s_setprio(1);
        #pragma unroll
        for (int n = 0; n < 4; ++n) {
            #pragma unroll
            for (int dh = 0; dh < 2; ++dh) {
                bf16x8 ak = *(const bf16x8*)(kbase + swz(n * 16 + l16, dh * 64 + lhi * 16));
                s[n] = __builtin_amdgcn_mfma_f32_16x16x32_bf16(ak, a_q[dh], s[n], 0, 0, 0);
            }
        }
        __builtin_amdgcn_s_setprio(0);

        // ---- mask only on the boundary tile (uniform branch) ----
        if (kt * 64 + 64 > valid) {
            #pragma unroll
            for (int n = 0; n < 4; ++n) {
                const int kbase_i = kt * 64 + n * 16 + lhi * 4;
                #pragma unroll
                for (int r = 0; r < 4; ++r)
                    if (kbase_i + r >= valid) s[n][r] = -1e30f;
            }
        }

        // ---- deferred-max online softmax, all state lane-local ----
        float lm = s[0][0];
        #pragma unroll
        for (int n = 0; n < 4; ++n)
            #pragma unroll
            for (int r = 0; r < 4; ++r) lm = fmaxf(lm, s[n][r]);
        if (__any(lm > m_r + DEFER_THR)) {   // rare, wave-uniform update
            float rm = fmaxf(lm, __shfl_xor(lm, 16, 64));
            rm = fmaxf(rm, __shfl_xor(rm, 32, 64));
            const float mnew  = fmaxf(m_r, rm);
            const float alpha = __builtin_amdgcn_exp2f(m_r - mnew);
            m_r = mnew;
            l_part *= alpha;
            #pragma unroll
            for (int t = 0; t < 4; ++t) o_acc[t] *= alpha;
        }

        // ---- P = 2^(s-m) -> bf16 B-fragments IN REGISTERS (no LDS):
        // cvt_pk packs pairs; permlane32+16 swaps move quads across lhi
        // groups so pb[kk] = keys kk*32 + lhi*8 + j (verified r11).
        bf16x8 pb[2];
        {
            float psum = 0.f;
            unsigned pk[4][2];
            #pragma unroll
            for (int n = 0; n < 4; ++n) {
                float e0 = __builtin_amdgcn_exp2f(s[n][0] - m_r);
                float e1 = __builtin_amdgcn_exp2f(s[n][1] - m_r);
                float e2 = __builtin_amdgcn_exp2f(s[n][2] - m_r);
                float e3 = __builtin_amdgcn_exp2f(s[n][3] - m_r);
                psum += (e0 + e1) + (e2 + e3);
                asm("v_cvt_pk_bf16_f32 %0, %1, %2" : "=v"(pk[n][0]) : "v"(e0), "v"(e1));
                asm("v_cvt_pk_bf16_f32 %0, %1, %2" : "=v"(pk[n][1]) : "v"(e2), "v"(e3));
            }
            l_part += psum;
            #pragma unroll
            for (int kk = 0; kk < 2; ++kk) {
                unsigned a0 = pk[2 * kk][0],     a1 = pk[2 * kk][1];
                unsigned b0 = pk[2 * kk + 1][0], b1 = pk[2 * kk + 1][1];
                asm("v_permlane32_swap_b32 %0, %1" : "+v"(a0), "+v"(b0));
                asm("v_permlane16_swap_b32 %0, %1" : "+v"(a0), "+v"(b0));
                asm("v_permlane32_swap_b32 %0, %1" : "+v"(a1), "+v"(b1));
                asm("v_permlane16_swap_b32 %0, %1" : "+v"(a1), "+v"(b1));
                u32x4 words = {a0, a1, b0, b1};   // j01, j23, j45, j67
                pb[kk] = __builtin_bit_cast(bf16x8, words);
            }
        }

        // ---- PV swapped: O^T += V^T P^T -> lane = q-col, d-rows ----
        __builtin_amdgcn_s_setprio(1);
        #pragma unroll
        for (int t = 0; t < 4; ++t) {
            #pragma unroll
            for (int kk = 0; kk < 2; ++kk) {
                bf16x8 vb = *(const bf16x8*)(vbase + swz(t * 16 + l16, kk * 64 + lhi * 16));
                o_acc[t] = __builtin_amdgcn_mfma_f32_16x16x32_bf16(vb, pb[kk], o_acc[t], 0, 0, 0);
            }
        }
        __builtin_amdgcn_s_setprio(0);

        // regs -> LDS for next tile; vmcnt paid HERE (after full compute phase)
        if (more) write_tile(cur ^ 1);
        cur ^= 1;
    }

    // ---- epilogue: finish l over the lhi group, divide, vector store ----
    float l = l_part;
    l += __shfl_xor(l, 16, 64);
    l += __shfl_xor(l, 32, 64);
    const float inv = 1.f / l;
    float* op = out + (((size_t)b * Q_ + qrow) * H_ + h) * D_;
    #pragma unroll
    for (int t = 0; t < 4; ++t) {
        f32x4 res = o_acc[t];
        #pragma unroll
        for (int r = 0; r < 4; ++r) res[r] *= inv;
        *(f32x4*)(op + t * 16 + lhi * 4) = res;
    }
}

extern "C" void kernel_launch(void* const* d_in, const int* in_sizes, int n_in,
                              void* d_out, int out_size, void* d_ws, size_t ws_size,
                              hipStream_t stream) {
    const float* qs = (const float*)d_in[0];
    const float* ks = (const float*)d_in[1];
    const float* vs = (const float*)d_in[2];
    const int*   vl = (const int*)d_in[3];
    float*       out = (float*)d_out;
    attn_fwd_kernel<<<dim3(512), 512, 0, stream>>>(qs, ks, vs, vl, out);
}

// Round 22
// 35.265 us; speedup vs baseline: 1.4075x; 1.0021x over previous
//
#include <hip/hip_runtime.h>

#define B_ 2
#define Q_ 2048
#define K_ 2048
#define H_ 16
#define D_ 64
#define HD_ (H_ * D_)

// Q pre-scale: (1/sqrt(64)) * log2(e)  -> scores in log2 units; softmax uses
// raw v_exp_f32 (2^x) with no per-element multiply.
#define QSCALE 0.18033688011112042f
#define DEFER_THR 10.0f   // log2-units; P bounded by 2^10, fine in bf16/f32

typedef __bf16 bf16_t;
typedef __attribute__((ext_vector_type(8))) __bf16 bf16x8;
typedef __attribute__((ext_vector_type(4))) __bf16 bf16x4;
typedef __attribute__((ext_vector_type(4))) float f32x4;
typedef __attribute__((ext_vector_type(4))) unsigned int u32x4;

// Raw barrier: drains LDS ops only; global register-prefetch stays in flight.
#define SBAR() do {                                         \
    __builtin_amdgcn_sched_barrier(0);                      \
    asm volatile("s_waitcnt lgkmcnt(0)" ::: "memory");      \
    __builtin_amdgcn_s_barrier();                           \
    __builtin_amdgcn_sched_barrier(0);                      \
} while (0)

// Swizzled byte offset for a [N][64] bf16 tile (row stride 128 B).
// XOR bits 4-6 with row&7: bijective, keeps 16B granules, kills bank conflicts.
__device__ __forceinline__ int swz(int row, int colByte) {
    return (row * 128 + colByte) ^ ((row & 7) << 4);
}

// FINAL CONVERGED FORM (r18 = r20, 35.3 us, reproduced twice): 512 thr /
// 8 waves / F=1 / BQ=128 / KVBLK=64, monolith. Techniques, each A/B-proven:
//  - XOR-swizzled K + transposed-V LDS tiles, conflict-free (r1: 1.4e7 -> 0)
//  - lgkm-only SBAR + cross-barrier register prefetch (r3-r5 frame)
//  - 8-wave TLP, K/V staging role split (r5: +36%)
//  - exp2-domain scores, deferred-max gate, lane-partial l (r6: +27%)
//  - swapped-operand QK^T/PV -> lane-local softmax state, vector stores (r7)
//  - P->B-fragments in registers via cvt_pk + permlane{32,16}_swap (r15: +6%;
//    numerics verified r11). SINGLE-ARG launch bounds only - two-arg capped
//    arch-VGPRs at 64 and spilled ~50 regs/thread (r9-r14).
//  - XCD remap v2: 2 heads/XCD L2 locality (FETCH 63.5->15.1 MB) with batch
//    flipped between co-resident blocks p/p+256 for short/long backfill (r18).
// Rejected by measurement: BQ=64 (r8), split-K (r9-r13), F=2 (r11-r14),
// two-half softmax pipeline (r16), same-batch XCD pairing (r17),
// KVBLK=128 (r19), l-via-ones-MFMA (r21: refcheck fail, codegen-level).
__global__ __launch_bounds__(512) void attn_fwd_kernel(
    const float* __restrict__ qs, const float* __restrict__ ks,
    const float* __restrict__ vs, const int* __restrict__ valid_lens,
    float* __restrict__ out)
{
    const int p    = blockIdx.x;
    const int xcd  = p & 7;
    const int slot = p >> 3;                  // 0..63
    const int qt   = slot & 15;               // q-tile within group
    const int h    = xcd * 2 + ((slot >> 4) & 1);
    const int b    = (slot >> 5) & 1;

    const int tid  = threadIdx.x;
    const int lane = tid & 63;
    const int l16  = lane & 15;
    const int lhi  = lane >> 4;    // 0..3

    const int valid  = valid_lens[b];
    const int ntiles = (valid + 63) >> 6;   // tiles fully past valid contribute exactly 0

    __shared__ bf16_t k_lds[2][64 * 64];    // [buf][key][d], swizzled
    __shared__ bf16_t v_lds[2][64 * 64];    // [buf][d][key] transposed, swizzled

    // ---- Q fragment (lane = row l16, k-dim d = dh*32+lhi*8+j), scale folded.
    const int    qrow = qt * 128 + (tid >> 6) * 16 + l16;
    const float* qp   = qs + (((size_t)b * Q_ + qrow) * H_ + h) * D_;
    bf16x8 a_q[2];
    #pragma unroll
    for (int dh = 0; dh < 2; ++dh) {
        const f32x4* q4 = (const f32x4*)(qp + dh * 32 + lhi * 8);
        f32x4 lo = q4[0], hi = q4[1];
        #pragma unroll
        for (int j = 0; j < 4; ++j) {
            a_q[dh][j]     = (bf16_t)(lo[j] * QSCALE);
            a_q[dh][4 + j] = (bf16_t)(hi[j] * QSCALE);
        }
    }

    // O accumulator (swapped PV C-layout): lane = q-col l16, d = t*16+lhi*4+r.
    f32x4 o_acc[4];
    #pragma unroll
    for (int t = 0; t < 4; ++t) o_acc[t] = (f32x4){0.f, 0.f, 0.f, 0.f};
    float m_r = -1e30f, l_part = 0.f;

    const float* kb = ks + ((size_t)b * K_ * H_ + h) * D_;
    const float* vg = vs + ((size_t)b * K_ * H_ + h) * D_;

    // staging role split (wave-uniform): waves 0-3 stage K, waves 4-7 stage V
    const bool kRole = (tid < 256);
    const int  st    = kRole ? tid : (tid - 256);   // 0..255
    const int  krow  = st >> 2;                     // 0..63 (key)
    const int  kcolf = (st & 3) * 16;               // float col base
    const int  vr    = (st & 15) * 4;               // key base (4 rows)
    const int  vc    = (st >> 4) * 4;               // d base (4 cols)

    f32x4 reg[4];   // in-flight next tile (lives across the barrier)

    auto issue_loads = [&](int kt) {
        if (kRole) {
            const float* ksrc = kb + (size_t)(kt * 64 + krow) * HD_ + kcolf;
            #pragma unroll
            for (int i = 0; i < 4; ++i) reg[i] = ((const f32x4*)ksrc)[i];
        } else {
            #pragma unroll
            for (int i = 0; i < 4; ++i)
                reg[i] = *(const f32x4*)(vg + (size_t)(kt * 64 + vr + i) * HD_ + vc);
        }
    };

    auto write_tile = [&](int bi) {
        if (kRole) {
            char* kdst = (char*)&k_lds[bi][0];
            bf16x8 lo, hi;
            #pragma unroll
            for (int j = 0; j < 4; ++j) {
                lo[j] = (bf16_t)reg[0][j]; lo[4 + j] = (bf16_t)reg[1][j];
                hi[j] = (bf16_t)reg[2][j]; hi[4 + j] = (bf16_t)reg[3][j];
            }
            *(bf16x8*)(kdst + swz(krow, kcolf * 2))      = lo;
            *(bf16x8*)(kdst + swz(krow, kcolf * 2 + 16)) = hi;
        } else {
            char* vdst = (char*)&v_lds[bi][0];
            #pragma unroll
            for (int j = 0; j < 4; ++j) {
                bf16x4 w;
                w[0] = (bf16_t)reg[0][j]; w[1] = (bf16_t)reg[1][j];
                w[2] = (bf16_t)reg[2][j]; w[3] = (bf16_t)reg[3][j];
                *(bf16x4*)(vdst + swz(vc + j, vr * 2)) = w;
            }
        }
    };

    // prologue: tile 0 straight to LDS
    issue_loads(0);
    write_tile(0);
    int cur = 0;

    for (int kt = 0; kt < ntiles; ++kt) {
        const bool more = (kt + 1 < ntiles);
        if (more) issue_loads(kt + 1);   // stays in flight across SBAR (no vmcnt drain)
        SBAR();

        char* const kbase = (char*)&k_lds[cur][0];
        char* const vbase = (char*)&v_lds[cur][0];

        // ---- S^T = K Q^T (swapped): lane = q-row l16, keys n*16+lhi*4+r.
        f32x4 s[4];
        #pragma unroll
        for (int n = 0; n < 4; ++n) s[n] = (f32x4){0.f, 0.f, 0.f, 0.f};
        __builtin_amdgcn_s_setprio(1);
        #pragma unroll
        for (int n = 0; n < 4; ++n) {
            #pragma unroll
            for (int dh = 0; dh < 2; ++dh) {
                bf16x8 ak = *(const bf16x8*)(kbase + swz(n * 16 + l16, dh * 64 + lhi * 16));
                s[n] = __builtin_amdgcn_mfma_f32_16x16x32_bf16(ak, a_q[dh], s[n], 0, 0, 0);
            }
        }
        __builtin_amdgcn_s_setprio(0);

        // ---- mask only on the boundary tile (uniform branch) ----
        if (kt * 64 + 64 > valid) {
            #pragma unroll
            for (int n = 0; n < 4; ++n) {
                const int kbase_i = kt * 64 + n * 16 + lhi * 4;
                #pragma unroll
                for (int r = 0; r < 4; ++r)
                    if (kbase_i + r >= valid) s[n][r] = -1e30f;
            }
        }

        // ---- deferred-max online softmax, all state lane-local ----
        float lm = s[0][0];
        #pragma unroll
        for (int n = 0; n < 4; ++n)
            #pragma unroll
            for (int r = 0; r < 4; ++r) lm = fmaxf(lm, s[n][r]);
        if (__any(lm > m_r + DEFER_THR)) {   // rare, wave-uniform update
            float rm = fmaxf(lm, __shfl_xor(lm, 16, 64));
            rm = fmaxf(rm, __shfl_xor(rm, 32, 64));
            const float mnew  = fmaxf(m_r, rm);
            const float alpha = __builtin_amdgcn_exp2f(m_r - mnew);
            m_r = mnew;
            l_part *= alpha;
            #pragma unroll
            for (int t = 0; t < 4; ++t) o_acc[t] *= alpha;
        }

        // ---- P = 2^(s-m) -> bf16 B-fragments IN REGISTERS (no LDS):
        // cvt_pk packs pairs; permlane32+16 swaps move quads across lhi
        // groups so pb[kk] = keys kk*32 + lhi*8 + j (verified r11).
        bf16x8 pb[2];
        {
            float psum = 0.f;
            unsigned pk[4][2];
            #pragma unroll
            for (int n = 0; n < 4; ++n) {
                float e0 = __builtin_amdgcn_exp2f(s[n][0] - m_r);
                float e1 = __builtin_amdgcn_exp2f(s[n][1] - m_r);
                float e2 = __builtin_amdgcn_exp2f(s[n][2] - m_r);
                float e3 = __builtin_amdgcn_exp2f(s[n][3] - m_r);
                psum += (e0 + e1) + (e2 + e3);
                asm("v_cvt_pk_bf16_f32 %0, %1, %2" : "=v"(pk[n][0]) : "v"(e0), "v"(e1));
                asm("v_cvt_pk_bf16_f32 %0, %1, %2" : "=v"(pk[n][1]) : "v"(e2), "v"(e3));
            }
            l_part += psum;
            #pragma unroll
            for (int kk = 0; kk < 2; ++kk) {
                unsigned a0 = pk[2 * kk][0],     a1 = pk[2 * kk][1];
                unsigned b0 = pk[2 * kk + 1][0], b1 = pk[2 * kk + 1][1];
                asm("v_permlane32_swap_b32 %0, %1" : "+v"(a0), "+v"(b0));
                asm("v_permlane16_swap_b32 %0, %1" : "+v"(a0), "+v"(b0));
                asm("v_permlane32_swap_b32 %0, %1" : "+v"(a1), "+v"(b1));
                asm("v_permlane16_swap_b32 %0, %1" : "+v"(a1), "+v"(b1));
                u32x4 words = {a0, a1, b0, b1};   // j01, j23, j45, j67
                pb[kk] = __builtin_bit_cast(bf16x8, words);
            }
        }

        // ---- PV swapped: O^T += V^T P^T -> lane = q-col, d-rows ----
        __builtin_amdgcn_s_setprio(1);
        #pragma unroll
        for (int t = 0; t < 4; ++t) {
            #pragma unroll
            for (int kk = 0; kk < 2; ++kk) {
                bf16x8 vb = *(const bf16x8*)(vbase + swz(t * 16 + l16, kk * 64 + lhi * 16));
                o_acc[t] = __builtin_amdgcn_mfma_f32_16x16x32_bf16(vb, pb[kk], o_acc[t], 0, 0, 0);
            }
        }
        __builtin_amdgcn_s_setprio(0);

        // regs -> LDS for next tile; vmcnt paid HERE (after full compute phase)
        if (more) write_tile(cur ^ 1);
        cur ^= 1;
    }

    // ---- epilogue: finish l over the lhi group, divide, vector store ----
    float l = l_part;
    l += __shfl_xor(l, 16, 64);
    l += __shfl_xor(l, 32, 64);
    const float inv = 1.f / l;
    float* op = out + (((size_t)b * Q_ + qrow) * H_ + h) * D_;
    #pragma unroll
    for (int t = 0; t < 4; ++t) {
        f32x4 res = o_acc[t];
        #pragma unroll
        for (int r = 0; r < 4; ++r) res[r] *= inv;
        *(f32x4*)(op + t * 16 + lhi * 4) = res;
    }
}

extern "C" void kernel_launch(void* const* d_in, const int* in_sizes, int n_in,
                              void* d_out, int out_size, void* d_ws, size_t ws_size,
                              hipStream_t stream) {
    const float* qs = (const float*)d_in[0];
    const float* ks = (const float*)d_in[1];
    const float* vs = (const float*)d_in[2];
    const int*   vl = (const int*)d_in[3];
    float*       out = (float*)d_out;
    attn_fwd_kernel<<<dim3(512), 512, 0, stream>>>(qs, ks, vs, vl, out);
}